// Round 4
// baseline (148.191 us; speedup 1.0000x reference)
//
#include <hip/hip_runtime.h>

#define N_NODES 100000
#define N_EDGES 3200000
#define N_FEAT  256
#define N_HID   64

// ---- bin partition geometry ----
#define BIN_SHIFT 9
#define BIN_W     512                       // target-nodes per bin
#define NBINS     196                       // ceil(N_NODES / BIN_W)
#define BIN_CAP   17408                     // mean 16327, sigma ~128 -> +8.4 sigma
#define NPART     2048                      // partition blocks
#define NE4       (N_EDGES / 4)             // 800000 int4-groups
#define I4PB      ((NE4 + NPART - 1) / NPART)   // 391 int4s per partition block

// ---------------------------------------------------------------------------
// W_comb[f] = sum_k W_gnn[f,k]*W_cls[k];  bias_y = b_gnn.W_cls + b_cls
// Also zeroes the bin cursor array (replaces a memset dispatch).
// ---------------------------------------------------------------------------
__global__ void k_wcomb(const float* __restrict__ Wg, const float* __restrict__ bg,
                        const float* __restrict__ Wc, const float* __restrict__ bc,
                        float* __restrict__ wcomb, float* __restrict__ biasy,
                        int* __restrict__ cursor) {
    int f = threadIdx.x;
    if (f < NBINS) cursor[f] = 0;
    float s = 0.f;
#pragma unroll
    for (int k = 0; k < N_HID; ++k) s += Wg[f * N_HID + k] * Wc[k];
    wcomb[f] = s;
    if (f == 0) {
        float b = 0.f;
        for (int k = 0; k < N_HID; ++k) b += bg[k] * Wc[k];
        *biasy = b + bc[0];
    }
}

// ---------------------------------------------------------------------------
// Wave-per-node dual dot product: pq[i] = { x[i].W_comb, x[i].W_est }
// ---------------------------------------------------------------------------
__global__ __launch_bounds__(256) void k_pq(const float* __restrict__ x,
                                            const float* __restrict__ West,
                                            const float* __restrict__ wcomb,
                                            float2* __restrict__ pq) {
    int node = (blockIdx.x * blockDim.x + threadIdx.x) >> 6;
    int lane = threadIdx.x & 63;
    if (node >= N_NODES) return;
    float4 v  = ((const float4*)(x + (size_t)node * N_FEAT))[lane];
    float4 we = ((const float4*)West)[lane];
    float4 wc = ((const float4*)wcomb)[lane];
    float ps = v.x * we.x + v.y * we.y + v.z * we.z + v.w * we.w;
    float qs = v.x * wc.x + v.y * wc.y + v.z * wc.z + v.w * wc.w;
#pragma unroll
    for (int off = 32; off > 0; off >>= 1) {
        ps += __shfl_down(ps, off);
        qs += __shfl_down(qs, off);
    }
    if (lane == 0) pq[node] = make_float2(qs, ps);   // .x = y-path, .y = s-path
}

// ---------------------------------------------------------------------------
// Partition: scatter edges into per-target-bin regions (int4 index loads).
// packed word = (local_target << 17) | src   (src < 2^17, local < 512)
// ---------------------------------------------------------------------------
__global__ __launch_bounds__(256) void k_part(const int4* __restrict__ row4,
                                              const int4* __restrict__ col4,
                                              int* __restrict__ cursor,
                                              unsigned int* __restrict__ grouped) {
    __shared__ int hist[NBINS];
    __shared__ int base[NBINS];
    int tid = threadIdx.x;
    for (int i = tid; i < NBINS; i += 256) hist[i] = 0;
    __syncthreads();
    int i0 = blockIdx.x * I4PB;
    int i1 = i0 + I4PB;
    if (i1 > NE4) i1 = NE4;
    for (int i = i0 + tid; i < i1; i += 256) {
        int4 c = col4[i];
        atomicAdd(&hist[c.x >> BIN_SHIFT], 1);
        atomicAdd(&hist[c.y >> BIN_SHIFT], 1);
        atomicAdd(&hist[c.z >> BIN_SHIFT], 1);
        atomicAdd(&hist[c.w >> BIN_SHIFT], 1);
    }
    __syncthreads();
    for (int i = tid; i < NBINS; i += 256) {
        int c = hist[i];
        base[i] = c ? atomicAdd(&cursor[i], c) : 0;
        hist[i] = 0;
    }
    __syncthreads();
    for (int i = i0 + tid; i < i1; i += 256) {
        int4 c = col4[i];
        int4 r = row4[i];
        int b0 = c.x >> BIN_SHIFT, b1 = c.y >> BIN_SHIFT,
            b2 = c.z >> BIN_SHIFT, b3 = c.w >> BIN_SHIFT;
        int s0 = base[b0] + atomicAdd(&hist[b0], 1);
        int s1 = base[b1] + atomicAdd(&hist[b1], 1);
        int s2 = base[b2] + atomicAdd(&hist[b2], 1);
        int s3 = base[b3] + atomicAdd(&hist[b3], 1);
        if (s0 < BIN_CAP)
            grouped[(size_t)b0 * BIN_CAP + s0] = ((unsigned)(c.x & (BIN_W - 1)) << 17) | (unsigned)r.x;
        if (s1 < BIN_CAP)
            grouped[(size_t)b1 * BIN_CAP + s1] = ((unsigned)(c.y & (BIN_W - 1)) << 17) | (unsigned)r.y;
        if (s2 < BIN_CAP)
            grouped[(size_t)b2 * BIN_CAP + s2] = ((unsigned)(c.z & (BIN_W - 1)) << 17) | (unsigned)r.z;
        if (s3 < BIN_CAP)
            grouped[(size_t)b3 * BIN_CAP + s3] = ((unsigned)(c.w & (BIN_W - 1)) << 17) | (unsigned)r.w;
    }
}

// ---------------------------------------------------------------------------
// Per-bin degree histogram (LDS) -> dinv, table = dinv * pq
// ---------------------------------------------------------------------------
__global__ __launch_bounds__(256) void k_bindeg(const int* __restrict__ cursor,
                                                const unsigned int* __restrict__ grouped,
                                                const float2* __restrict__ pq,
                                                float* __restrict__ dinv,
                                                float2* __restrict__ table) {
    __shared__ int dh[BIN_W];
    int b = blockIdx.x, tid = threadIdx.x;
    for (int i = tid; i < BIN_W; i += 256) dh[i] = 0;
    __syncthreads();
    int cnt = cursor[b];
    if (cnt > BIN_CAP) cnt = BIN_CAP;
    const unsigned int* g = grouped + (size_t)b * BIN_CAP;
    for (int i = tid; i < cnt; i += 256) atomicAdd(&dh[g[i] >> 17], 1);
    __syncthreads();
    for (int l = tid; l < BIN_W; l += 256) {
        int node = b * BIN_W + l;
        if (node < N_NODES) {
            float di = rsqrtf((float)(dh[l] + 1));   // +1 self-loop
            dinv[node] = di;
            float2 v = pq[node];
            table[node] = make_float2(di * v.x, di * v.y);
        }
    }
}

// ---------------------------------------------------------------------------
// Per-bin accumulate: 4KB LDS tile, ds_add_f32 atomics (on-CU, no fabric),
// self-loop pre-added, finalize fused (out = dinv*tile + bias).
// ---------------------------------------------------------------------------
__global__ __launch_bounds__(1024) void k_binacc(const int* __restrict__ cursor,
                                                 const unsigned int* __restrict__ grouped,
                                                 const float2* __restrict__ table,
                                                 const float* __restrict__ dinv,
                                                 const float* __restrict__ biasy,
                                                 const float* __restrict__ best,
                                                 float* __restrict__ out) {
    __shared__ float2 tile[BIN_W];
    int b = blockIdx.x, tid = threadIdx.x;
    for (int l = tid; l < BIN_W; l += 1024) {
        int node = b * BIN_W + l;
        tile[l] = (node < N_NODES) ? table[node] : make_float2(0.f, 0.f);
    }
    __syncthreads();
    int cnt = cursor[b];
    if (cnt > BIN_CAP) cnt = BIN_CAP;
    const unsigned int* g = grouped + (size_t)b * BIN_CAP;
    for (int i = tid; i < cnt; i += 1024) {
        unsigned int v = g[i];
        float2 t = table[v & 0x1FFFFu];
        int lc = v >> 17;
        atomicAdd(&tile[lc].x, t.x);
        atomicAdd(&tile[lc].y, t.y);
    }
    __syncthreads();
    float by = biasy[0], bs = best[0];
    for (int l = tid; l < BIN_W; l += 1024) {
        int node = b * BIN_W + l;
        if (node < N_NODES) {
            float di = dinv[node];
            out[node]           = di * tile[l].x + by;
            out[N_NODES + node] = di * tile[l].y + bs;
        }
    }
}

// ===========================================================================
// Fallback pipeline (proven ~500us) used only if ws_size is too small.
// ===========================================================================
__global__ __launch_bounds__(256) void k_deg_fb(const int* __restrict__ col,
                                                int* __restrict__ deg) {
    int e = blockIdx.x * blockDim.x + threadIdx.x;
    if (e < N_EDGES) atomicAdd(&deg[col[e]], 1);
}
__global__ __launch_bounds__(256) void k_pqtable_fb(
        const float* __restrict__ x, const float* __restrict__ West,
        const float* __restrict__ wcomb, const int* __restrict__ deg,
        float* __restrict__ dinv, float2* __restrict__ table,
        float2* __restrict__ acc) {
    int node = (blockIdx.x * blockDim.x + threadIdx.x) >> 6;
    int lane = threadIdx.x & 63;
    if (node >= N_NODES) return;
    float4 v  = ((const float4*)(x + (size_t)node * N_FEAT))[lane];
    float4 we = ((const float4*)West)[lane];
    float4 wc = ((const float4*)wcomb)[lane];
    float ps = v.x * we.x + v.y * we.y + v.z * we.z + v.w * we.w;
    float qs = v.x * wc.x + v.y * wc.y + v.z * wc.z + v.w * wc.w;
#pragma unroll
    for (int off = 32; off > 0; off >>= 1) {
        ps += __shfl_down(ps, off);
        qs += __shfl_down(qs, off);
    }
    if (lane == 0) {
        float di = rsqrtf((float)(deg[node] + 1));
        float2 t = make_float2(di * qs, di * ps);
        dinv[node] = di; table[node] = t; acc[node] = t;
    }
}
__global__ __launch_bounds__(256) void k_edge_fb(const int* __restrict__ ei,
                                                 const float2* __restrict__ table,
                                                 float2* __restrict__ acc) {
    int e = blockIdx.x * blockDim.x + threadIdx.x;
    if (e >= N_EDGES) return;
    float2 t = table[ei[e]];
    int c = ei[N_EDGES + e];
    unsafeAtomicAdd(&acc[c].x, t.x);
    unsafeAtomicAdd(&acc[c].y, t.y);
}
__global__ __launch_bounds__(256) void k_fin_fb(
        const float* __restrict__ dinv, const float2* __restrict__ acc,
        const float* __restrict__ biasy, const float* __restrict__ best,
        float* __restrict__ out) {
    int i = blockIdx.x * blockDim.x + threadIdx.x;
    if (i >= N_NODES) return;
    float di = dinv[i];
    float2 a = acc[i];
    out[i]           = di * a.x + biasy[0];
    out[N_NODES + i] = di * a.y + best[0];
}

extern "C" void kernel_launch(void* const* d_in, const int* in_sizes, int n_in,
                              void* d_out, int out_size, void* d_ws, size_t ws_size,
                              hipStream_t stream) {
    const int*   ei   = (const int*)d_in[0];
    const float* x    = (const float*)d_in[1];
    const float* West = (const float*)d_in[2];
    const float* best = (const float*)d_in[3];
    const float* Wg   = (const float*)d_in[4];
    const float* bg   = (const float*)d_in[5];
    const float* Wc   = (const float*)d_in[6];
    const float* bc   = (const float*)d_in[7];
    float* out = (float*)d_out;

    // ---- workspace layout (bytes) ----
    char* ws = (char*)d_ws;
    float*  wcomb = (float*)ws;                       // 256 f          @ 0
    float*  biasy = wcomb + 256;                      // 1 f
    float2* pq    = (float2*)(ws + 2048);             // N f2  (800000 B)
    float2* table = (float2*)(ws + 802048);           // N f2  (800000 B)
    float*  dinv  = (float*)(ws + 1602048);           // N f   (400000 B)
    int*    cursor= (int*)(ws + 2002048);             // NBINS i (784 B)
    unsigned int* grouped = (unsigned int*)(ws + 2003072); // NBINS*BIN_CAP u32
    size_t need = 2003072 + (size_t)NBINS * BIN_CAP * 4;   // ~15.65 MB

    if (ws_size >= need) {
        k_wcomb<<<1, 256, 0, stream>>>(Wg, bg, Wc, bc, wcomb, biasy, cursor);
        k_pq<<<(N_NODES * 64 + 255) / 256, 256, 0, stream>>>(x, West, wcomb, pq);
        k_part<<<NPART, 256, 0, stream>>>((const int4*)ei,
                                          (const int4*)(ei + N_EDGES),
                                          cursor, grouped);
        k_bindeg<<<NBINS, 256, 0, stream>>>(cursor, grouped, pq, dinv, table);
        k_binacc<<<NBINS, 1024, 0, stream>>>(cursor, grouped, table, dinv,
                                             biasy, best, out);
    } else {
        // fallback: global-atomic pipeline (needs ~2.4 MB)
        int*    deg  = (int*)(ws + 2048 + 800000 * 2 + 400000);
        float2* acc  = pq;       // reuse
        float2* tbl  = table;
        hipMemsetAsync(deg, 0, N_NODES * sizeof(int), stream);
        k_wcomb<<<1, 256, 0, stream>>>(Wg, bg, Wc, bc, wcomb, biasy, (int*)(ws + 2002048));
        k_deg_fb<<<(N_EDGES + 255) / 256, 256, 0, stream>>>(ei + N_EDGES, deg);
        k_pqtable_fb<<<(N_NODES * 64 + 255) / 256, 256, 0, stream>>>(
            x, West, wcomb, deg, dinv, tbl, acc);
        k_edge_fb<<<(N_EDGES + 255) / 256, 256, 0, stream>>>(ei, tbl, acc);
        k_fin_fb<<<(N_NODES + 255) / 256, 256, 0, stream>>>(dinv, acc, biasy, best, out);
    }
}

// Round 5
// 119.153 us; speedup vs baseline: 1.2437x; 1.2437x over previous
//
#include <hip/hip_runtime.h>

#define N_NODES 100000
#define N_EDGES 3200000
#define N_FEAT  256
#define N_HID   64

// ---- bin partition geometry ----
#define BIN_SHIFT 9
#define BIN_W     512                       // target-nodes per bin
#define NBINS     196                       // ceil(N_NODES / BIN_W)
#define BIN_CAP   17408                     // mean 16384, sigma ~128 -> +8 sigma
#define NPART     500                       // partition blocks
#define EPB       6400                      // edges per block (exact: 500*6400 = 3.2M)
#define I4PB      1600                      // int4 groups per block

// ---------------------------------------------------------------------------
// W_comb[f] = sum_k W_gnn[f,k]*W_cls[k];  bias_y = b_gnn.W_cls + b_cls
// Also zeroes the bin cursor array (replaces a memset dispatch).
// ---------------------------------------------------------------------------
__global__ void k_wcomb(const float* __restrict__ Wg, const float* __restrict__ bg,
                        const float* __restrict__ Wc, const float* __restrict__ bc,
                        float* __restrict__ wcomb, float* __restrict__ biasy,
                        int* __restrict__ cursor) {
    int f = threadIdx.x;
    if (f < NBINS) cursor[f] = 0;
    float s = 0.f;
#pragma unroll
    for (int k = 0; k < N_HID; ++k) s += Wg[f * N_HID + k] * Wc[k];
    wcomb[f] = s;
    if (f == 0) {
        float b = 0.f;
        for (int k = 0; k < N_HID; ++k) b += bg[k] * Wc[k];
        *biasy = b + bc[0];
    }
}

// ---------------------------------------------------------------------------
// Wave-per-node dual dot product: pq[i] = { x[i].W_comb, x[i].W_est }
// ---------------------------------------------------------------------------
__global__ __launch_bounds__(256) void k_pq(const float* __restrict__ x,
                                            const float* __restrict__ West,
                                            const float* __restrict__ wcomb,
                                            float2* __restrict__ pq) {
    int node = (blockIdx.x * blockDim.x + threadIdx.x) >> 6;
    int lane = threadIdx.x & 63;
    if (node >= N_NODES) return;
    float4 v  = ((const float4*)(x + (size_t)node * N_FEAT))[lane];
    float4 we = ((const float4*)West)[lane];
    float4 wc = ((const float4*)wcomb)[lane];
    float ps = v.x * we.x + v.y * we.y + v.z * we.z + v.w * we.w;
    float qs = v.x * wc.x + v.y * wc.y + v.z * wc.z + v.w * wc.w;
#pragma unroll
    for (int off = 32; off > 0; off >>= 1) {
        ps += __shfl_down(ps, off);
        qs += __shfl_down(qs, off);
    }
    if (lane == 0) pq[node] = make_float2(qs, ps);   // .x = y-path, .y = s-path
}

// ---------------------------------------------------------------------------
// Partition, LDS-staged:
//   A) LDS histogram of target bins (non-returning ds_add)
//   B) block scan -> local starts; one cursor atomic per non-empty bin
//   C) scatter packed words into LDS staging (random traffic stays on-CU)
//   D) wave-per-bin contiguous burst copy LDS -> grouped (coalesced lines)
// packed word = (local_target << 17) | src   (src < 2^17, local < 512)
// ---------------------------------------------------------------------------
__global__ __launch_bounds__(256) void k_part(const int4* __restrict__ row4,
                                              const int4* __restrict__ col4,
                                              int* __restrict__ cursor,
                                              unsigned int* __restrict__ grouped) {
    __shared__ int cnts[256];
    __shared__ int lstart[256];
    __shared__ int lcount[256];
    __shared__ int gbase[256];
    __shared__ int scan[256];
    __shared__ unsigned int stage[EPB];          // 25.6 KB
    int tid = threadIdx.x;
    lcount[tid] = 0;
    __syncthreads();
    int i0 = blockIdx.x * I4PB;

    // A: histogram
    for (int i = i0 + tid; i < i0 + I4PB; i += 256) {
        int4 c = col4[i];
        atomicAdd(&lcount[c.x >> BIN_SHIFT], 1);
        atomicAdd(&lcount[c.y >> BIN_SHIFT], 1);
        atomicAdd(&lcount[c.z >> BIN_SHIFT], 1);
        atomicAdd(&lcount[c.w >> BIN_SHIFT], 1);
    }
    __syncthreads();

    // B: block-wide inclusive scan (Hillis-Steele), then exclusive starts
    int cnt = lcount[tid];
    cnts[tid] = cnt;
    scan[tid] = cnt;
    __syncthreads();
#pragma unroll
    for (int d = 1; d < 256; d <<= 1) {
        int t = (tid >= d) ? scan[tid - d] : 0;
        __syncthreads();
        scan[tid] += t;
        __syncthreads();
    }
    lstart[tid] = scan[tid] - cnt;
    gbase[tid]  = (tid < NBINS && cnt > 0) ? atomicAdd(&cursor[tid], cnt) : 0;
    lcount[tid] = 0;
    __syncthreads();

    // C: scatter into LDS staging
    for (int i = i0 + tid; i < i0 + I4PB; i += 256) {
        int4 c = col4[i];
        int4 r = row4[i];
        int b0 = c.x >> BIN_SHIFT; int s0 = lstart[b0] + atomicAdd(&lcount[b0], 1);
        stage[s0] = ((unsigned)(c.x & (BIN_W - 1)) << 17) | (unsigned)r.x;
        int b1 = c.y >> BIN_SHIFT; int s1 = lstart[b1] + atomicAdd(&lcount[b1], 1);
        stage[s1] = ((unsigned)(c.y & (BIN_W - 1)) << 17) | (unsigned)r.y;
        int b2 = c.z >> BIN_SHIFT; int s2 = lstart[b2] + atomicAdd(&lcount[b2], 1);
        stage[s2] = ((unsigned)(c.z & (BIN_W - 1)) << 17) | (unsigned)r.z;
        int b3 = c.w >> BIN_SHIFT; int s3 = lstart[b3] + atomicAdd(&lcount[b3], 1);
        stage[s3] = ((unsigned)(c.w & (BIN_W - 1)) << 17) | (unsigned)r.w;
    }
    __syncthreads();

    // D: coalesced burst copy, one wave per bin (runs avg ~32)
    int wid = tid >> 6, lane = tid & 63;
    for (int b = wid; b < NBINS; b += 4) {
        int s = lstart[b], len = cnts[b], gb = gbase[b];
        unsigned int* dst = grouped + (size_t)b * BIN_CAP;
        for (int off = lane; off < len; off += 64) {
            int g = gb + off;
            if (g < BIN_CAP) dst[g] = stage[s + off];
        }
    }
}

// ---------------------------------------------------------------------------
// Per-bin degree histogram (LDS) -> dinv, table = dinv * pq
// ---------------------------------------------------------------------------
__global__ __launch_bounds__(256) void k_bindeg(const int* __restrict__ cursor,
                                                const unsigned int* __restrict__ grouped,
                                                const float2* __restrict__ pq,
                                                float* __restrict__ dinv,
                                                float2* __restrict__ table) {
    __shared__ int dh[BIN_W];
    int b = blockIdx.x, tid = threadIdx.x;
    for (int i = tid; i < BIN_W; i += 256) dh[i] = 0;
    __syncthreads();
    int cnt = cursor[b];
    if (cnt > BIN_CAP) cnt = BIN_CAP;
    const unsigned int* g = grouped + (size_t)b * BIN_CAP;
    for (int i = tid; i < cnt; i += 256) atomicAdd(&dh[g[i] >> 17], 1);
    __syncthreads();
    for (int l = tid; l < BIN_W; l += 256) {
        int node = b * BIN_W + l;
        if (node < N_NODES) {
            float di = rsqrtf((float)(dh[l] + 1));   // +1 self-loop
            dinv[node] = di;
            float2 v = pq[node];
            table[node] = make_float2(di * v.x, di * v.y);
        }
    }
}

// ---------------------------------------------------------------------------
// Per-bin accumulate: 4KB LDS tile, ds_add_f32 atomics (on-CU, no fabric),
// self-loop pre-added, finalize fused (out = dinv*tile + bias).
// ---------------------------------------------------------------------------
__global__ __launch_bounds__(1024) void k_binacc(const int* __restrict__ cursor,
                                                 const unsigned int* __restrict__ grouped,
                                                 const float2* __restrict__ table,
                                                 const float* __restrict__ dinv,
                                                 const float* __restrict__ biasy,
                                                 const float* __restrict__ best,
                                                 float* __restrict__ out) {
    __shared__ float2 tile[BIN_W];
    int b = blockIdx.x, tid = threadIdx.x;
    for (int l = tid; l < BIN_W; l += 1024) {
        int node = b * BIN_W + l;
        tile[l] = (node < N_NODES) ? table[node] : make_float2(0.f, 0.f);
    }
    __syncthreads();
    int cnt = cursor[b];
    if (cnt > BIN_CAP) cnt = BIN_CAP;
    const unsigned int* g = grouped + (size_t)b * BIN_CAP;
    for (int i = tid; i < cnt; i += 1024) {
        unsigned int v = g[i];
        float2 t = table[v & 0x1FFFFu];
        int lc = v >> 17;
        atomicAdd(&tile[lc].x, t.x);
        atomicAdd(&tile[lc].y, t.y);
    }
    __syncthreads();
    float by = biasy[0], bs = best[0];
    for (int l = tid; l < BIN_W; l += 1024) {
        int node = b * BIN_W + l;
        if (node < N_NODES) {
            float di = dinv[node];
            out[node]           = di * tile[l].x + by;
            out[N_NODES + node] = di * tile[l].y + bs;
        }
    }
}

// ===========================================================================
// Fallback pipeline (proven ~500us) used only if ws_size is too small.
// ===========================================================================
__global__ __launch_bounds__(256) void k_deg_fb(const int* __restrict__ col,
                                                int* __restrict__ deg) {
    int e = blockIdx.x * blockDim.x + threadIdx.x;
    if (e < N_EDGES) atomicAdd(&deg[col[e]], 1);
}
__global__ __launch_bounds__(256) void k_pqtable_fb(
        const float* __restrict__ x, const float* __restrict__ West,
        const float* __restrict__ wcomb, const int* __restrict__ deg,
        float* __restrict__ dinv, float2* __restrict__ table,
        float2* __restrict__ acc) {
    int node = (blockIdx.x * blockDim.x + threadIdx.x) >> 6;
    int lane = threadIdx.x & 63;
    if (node >= N_NODES) return;
    float4 v  = ((const float4*)(x + (size_t)node * N_FEAT))[lane];
    float4 we = ((const float4*)West)[lane];
    float4 wc = ((const float4*)wcomb)[lane];
    float ps = v.x * we.x + v.y * we.y + v.z * we.z + v.w * we.w;
    float qs = v.x * wc.x + v.y * wc.y + v.z * wc.z + v.w * wc.w;
#pragma unroll
    for (int off = 32; off > 0; off >>= 1) {
        ps += __shfl_down(ps, off);
        qs += __shfl_down(qs, off);
    }
    if (lane == 0) {
        float di = rsqrtf((float)(deg[node] + 1));
        float2 t = make_float2(di * qs, di * ps);
        dinv[node] = di; table[node] = t; acc[node] = t;
    }
}
__global__ __launch_bounds__(256) void k_edge_fb(const int* __restrict__ ei,
                                                 const float2* __restrict__ table,
                                                 float2* __restrict__ acc) {
    int e = blockIdx.x * blockDim.x + threadIdx.x;
    if (e >= N_EDGES) return;
    float2 t = table[ei[e]];
    int c = ei[N_EDGES + e];
    unsafeAtomicAdd(&acc[c].x, t.x);
    unsafeAtomicAdd(&acc[c].y, t.y);
}
__global__ __launch_bounds__(256) void k_fin_fb(
        const float* __restrict__ dinv, const float2* __restrict__ acc,
        const float* __restrict__ biasy, const float* __restrict__ best,
        float* __restrict__ out) {
    int i = blockIdx.x * blockDim.x + threadIdx.x;
    if (i >= N_NODES) return;
    float di = dinv[i];
    float2 a = acc[i];
    out[i]           = di * a.x + biasy[0];
    out[N_NODES + i] = di * a.y + best[0];
}

extern "C" void kernel_launch(void* const* d_in, const int* in_sizes, int n_in,
                              void* d_out, int out_size, void* d_ws, size_t ws_size,
                              hipStream_t stream) {
    const int*   ei   = (const int*)d_in[0];
    const float* x    = (const float*)d_in[1];
    const float* West = (const float*)d_in[2];
    const float* best = (const float*)d_in[3];
    const float* Wg   = (const float*)d_in[4];
    const float* bg   = (const float*)d_in[5];
    const float* Wc   = (const float*)d_in[6];
    const float* bc   = (const float*)d_in[7];
    float* out = (float*)d_out;

    // ---- workspace layout (bytes) ----
    char* ws = (char*)d_ws;
    float*  wcomb = (float*)ws;                       // 256 f          @ 0
    float*  biasy = wcomb + 256;                      // 1 f
    float2* pq    = (float2*)(ws + 2048);             // N f2  (800000 B)
    float2* table = (float2*)(ws + 802048);           // N f2  (800000 B)
    float*  dinv  = (float*)(ws + 1602048);           // N f   (400000 B)
    int*    cursor= (int*)(ws + 2002048);             // NBINS i (784 B)
    unsigned int* grouped = (unsigned int*)(ws + 2003072); // NBINS*BIN_CAP u32
    size_t need = 2003072 + (size_t)NBINS * BIN_CAP * 4;   // ~15.65 MB

    if (ws_size >= need) {
        k_wcomb<<<1, 256, 0, stream>>>(Wg, bg, Wc, bc, wcomb, biasy, cursor);
        k_pq<<<(N_NODES * 64 + 255) / 256, 256, 0, stream>>>(x, West, wcomb, pq);
        k_part<<<NPART, 256, 0, stream>>>((const int4*)ei,
                                          (const int4*)(ei + N_EDGES),
                                          cursor, grouped);
        k_bindeg<<<NBINS, 256, 0, stream>>>(cursor, grouped, pq, dinv, table);
        k_binacc<<<NBINS, 1024, 0, stream>>>(cursor, grouped, table, dinv,
                                             biasy, best, out);
    } else {
        // fallback: global-atomic pipeline (needs ~2.4 MB)
        int*    deg  = (int*)(ws + 2048 + 800000 * 2 + 400000);
        float2* acc  = pq;       // reuse
        float2* tbl  = table;
        hipMemsetAsync(deg, 0, N_NODES * sizeof(int), stream);
        k_wcomb<<<1, 256, 0, stream>>>(Wg, bg, Wc, bc, wcomb, biasy, (int*)(ws + 2002048));
        k_deg_fb<<<(N_EDGES + 255) / 256, 256, 0, stream>>>(ei + N_EDGES, deg);
        k_pqtable_fb<<<(N_NODES * 64 + 255) / 256, 256, 0, stream>>>(
            x, West, wcomb, deg, dinv, tbl, acc);
        k_edge_fb<<<(N_EDGES + 255) / 256, 256, 0, stream>>>(ei, tbl, acc);
        k_fin_fb<<<(N_NODES + 255) / 256, 256, 0, stream>>>(dinv, acc, biasy, best, out);
    }
}

// Round 6
// 101.134 us; speedup vs baseline: 1.4653x; 1.1782x over previous
//
#include <hip/hip_runtime.h>

#define N_NODES 100000
#define N_EDGES 3200000
#define N_FEAT  256
#define N_HID   64

// ---- bin partition geometry ----
#define NBINS     256                       // one bin per CU for bindeg/binacc
#define BIN_W     391                       // ceil(100000/256); last bin has 295 nodes
#define BIN_CAP   13568                     // mean 12512, sigma ~112 -> +9.4 sigma
#define NPART     500                       // partition blocks
#define EPB       6400                      // edges per block (500*6400 = 3.2M exact)
#define I4PB      1600                      // int4 groups per block
#define NPQ       25000                     // pq blocks (4 nodes each)

// ---------------------------------------------------------------------------
// W_comb[f] = sum_k W_gnn[f,k]*W_cls[k];  bias_y = b_gnn.W_cls + b_cls
// Also zeroes the bin cursor array (replaces a memset dispatch).
// ---------------------------------------------------------------------------
__global__ void k_wcomb(const float* __restrict__ Wg, const float* __restrict__ bg,
                        const float* __restrict__ Wc, const float* __restrict__ bc,
                        float* __restrict__ wcomb, float* __restrict__ biasy,
                        int* __restrict__ cursor) {
    int f = threadIdx.x;
    if (f < NBINS) cursor[f] = 0;
    float s = 0.f;
#pragma unroll
    for (int k = 0; k < N_HID; ++k) s += Wg[f * N_HID + k] * Wc[k];
    wcomb[f] = s;
    if (f == 0) {
        float b = 0.f;
        for (int k = 0; k < N_HID; ++k) b += bg[k] * Wc[k];
        *biasy = b + bc[0];
    }
}

// ---------------------------------------------------------------------------
// Fused heterogeneous kernel:
//   blocks [0, NPART)        : LDS-staged edge partition (LDS/latency-bound)
//   blocks [NPART, NPART+NPQ): wave-per-node dual dot product (HBM-bound)
// The two workloads co-schedule on each CU; pq's HBM streaming hides under
// part's LDS-atomic phases.
// packed word = (local_target << 17) | src   (src < 2^17, local < 391)
// ---------------------------------------------------------------------------
__global__ __launch_bounds__(256) void k_pqpart(
        const float* __restrict__ x, const float* __restrict__ West,
        const float* __restrict__ wcomb, float2* __restrict__ pq,
        const int4* __restrict__ row4, const int4* __restrict__ col4,
        int* __restrict__ cursor, unsigned int* __restrict__ grouped) {
    __shared__ int cnts[256];
    __shared__ int lstart[256];
    __shared__ int lcount[256];
    __shared__ int gbase[256];
    __shared__ int scan[256];
    __shared__ unsigned int stage[EPB];          // 25.6 KB

    int tid = threadIdx.x;

    if (blockIdx.x >= NPART) {
        // ---------------- pq branch ----------------
        int node = (((int)blockIdx.x - NPART) << 2) + (tid >> 6);
        int lane = tid & 63;
        if (node >= N_NODES) return;
        float4 v  = ((const float4*)(x + (size_t)node * N_FEAT))[lane];
        float4 we = ((const float4*)West)[lane];
        float4 wc = ((const float4*)wcomb)[lane];
        float ps = v.x * we.x + v.y * we.y + v.z * we.z + v.w * we.w;
        float qs = v.x * wc.x + v.y * wc.y + v.z * wc.z + v.w * wc.w;
#pragma unroll
        for (int off = 32; off > 0; off >>= 1) {
            ps += __shfl_down(ps, off);
            qs += __shfl_down(qs, off);
        }
        if (lane == 0) pq[node] = make_float2(qs, ps);  // .x = y-path, .y = s-path
        return;
    }

    // ---------------- partition branch ----------------
    lcount[tid] = 0;
    __syncthreads();
    int i0 = blockIdx.x * I4PB;

    // A: histogram of target bins
    for (int i = i0 + tid; i < i0 + I4PB; i += 256) {
        int4 c = col4[i];
        atomicAdd(&lcount[c.x / BIN_W], 1);
        atomicAdd(&lcount[c.y / BIN_W], 1);
        atomicAdd(&lcount[c.z / BIN_W], 1);
        atomicAdd(&lcount[c.w / BIN_W], 1);
    }
    __syncthreads();

    // B: block-wide inclusive scan (Hillis-Steele) -> exclusive local starts
    int cnt = lcount[tid];
    cnts[tid] = cnt;
    scan[tid] = cnt;
    __syncthreads();
#pragma unroll
    for (int d = 1; d < 256; d <<= 1) {
        int t = (tid >= d) ? scan[tid - d] : 0;
        __syncthreads();
        scan[tid] += t;
        __syncthreads();
    }
    lstart[tid] = scan[tid] - cnt;
    gbase[tid]  = (cnt > 0) ? atomicAdd(&cursor[tid], cnt) : 0;
    lcount[tid] = 0;
    __syncthreads();

    // C: scatter packed words into LDS staging
    for (int i = i0 + tid; i < i0 + I4PB; i += 256) {
        int4 c = col4[i];
        int4 r = row4[i];
        int b0 = c.x / BIN_W; int s0 = lstart[b0] + atomicAdd(&lcount[b0], 1);
        stage[s0] = ((unsigned)(c.x - b0 * BIN_W) << 17) | (unsigned)r.x;
        int b1 = c.y / BIN_W; int s1 = lstart[b1] + atomicAdd(&lcount[b1], 1);
        stage[s1] = ((unsigned)(c.y - b1 * BIN_W) << 17) | (unsigned)r.y;
        int b2 = c.z / BIN_W; int s2 = lstart[b2] + atomicAdd(&lcount[b2], 1);
        stage[s2] = ((unsigned)(c.z - b2 * BIN_W) << 17) | (unsigned)r.z;
        int b3 = c.w / BIN_W; int s3 = lstart[b3] + atomicAdd(&lcount[b3], 1);
        stage[s3] = ((unsigned)(c.w - b3 * BIN_W) << 17) | (unsigned)r.w;
    }
    __syncthreads();

    // D: coalesced burst copy, one wave per bin (runs avg ~25)
    int wid = tid >> 6, lane = tid & 63;
    for (int b = wid; b < NBINS; b += 4) {
        int s = lstart[b], len = cnts[b], gb = gbase[b];
        unsigned int* dst = grouped + (size_t)b * BIN_CAP;
        for (int off = lane; off < len; off += 64) {
            int g = gb + off;
            if (g < BIN_CAP) dst[g] = stage[s + off];
        }
    }
}

// ---------------------------------------------------------------------------
// Per-bin degree histogram (LDS) -> dinv, table = dinv * pq
// ---------------------------------------------------------------------------
__global__ __launch_bounds__(256) void k_bindeg(const int* __restrict__ cursor,
                                                const unsigned int* __restrict__ grouped,
                                                const float2* __restrict__ pq,
                                                float* __restrict__ dinv,
                                                float2* __restrict__ table) {
    __shared__ int dh[BIN_W];
    int b = blockIdx.x, tid = threadIdx.x;
    for (int i = tid; i < BIN_W; i += 256) dh[i] = 0;
    __syncthreads();
    int cnt = cursor[b];
    if (cnt > BIN_CAP) cnt = BIN_CAP;
    const unsigned int* g = grouped + (size_t)b * BIN_CAP;
    for (int i = tid; i < cnt; i += 256) atomicAdd(&dh[g[i] >> 17], 1);
    __syncthreads();
    for (int l = tid; l < BIN_W; l += 256) {
        int node = b * BIN_W + l;
        if (node < N_NODES) {
            float di = rsqrtf((float)(dh[l] + 1));   // +1 self-loop
            dinv[node] = di;
            float2 v = pq[node];
            table[node] = make_float2(di * v.x, di * v.y);
        }
    }
}

// ---------------------------------------------------------------------------
// Per-bin accumulate: LDS tile, ds_add_f32 atomics (on-CU, no fabric),
// self-loop pre-added, finalize fused (out = dinv*tile + bias).
// ---------------------------------------------------------------------------
__global__ __launch_bounds__(1024) void k_binacc(const int* __restrict__ cursor,
                                                 const unsigned int* __restrict__ grouped,
                                                 const float2* __restrict__ table,
                                                 const float* __restrict__ dinv,
                                                 const float* __restrict__ biasy,
                                                 const float* __restrict__ best,
                                                 float* __restrict__ out) {
    __shared__ float2 tile[BIN_W];
    int b = blockIdx.x, tid = threadIdx.x;
    for (int l = tid; l < BIN_W; l += 1024) {
        int node = b * BIN_W + l;
        tile[l] = (node < N_NODES) ? table[node] : make_float2(0.f, 0.f);
    }
    __syncthreads();
    int cnt = cursor[b];
    if (cnt > BIN_CAP) cnt = BIN_CAP;
    const unsigned int* g = grouped + (size_t)b * BIN_CAP;
    for (int i = tid; i < cnt; i += 1024) {
        unsigned int v = g[i];
        float2 t = table[v & 0x1FFFFu];
        int lc = v >> 17;
        atomicAdd(&tile[lc].x, t.x);
        atomicAdd(&tile[lc].y, t.y);
    }
    __syncthreads();
    float by = biasy[0], bs = best[0];
    for (int l = tid; l < BIN_W; l += 1024) {
        int node = b * BIN_W + l;
        if (node < N_NODES) {
            float di = dinv[node];
            out[node]           = di * tile[l].x + by;
            out[N_NODES + node] = di * tile[l].y + bs;
        }
    }
}

// ===========================================================================
// Fallback pipeline (proven ~500us) used only if ws_size is too small.
// ===========================================================================
__global__ __launch_bounds__(256) void k_deg_fb(const int* __restrict__ col,
                                                int* __restrict__ deg) {
    int e = blockIdx.x * blockDim.x + threadIdx.x;
    if (e < N_EDGES) atomicAdd(&deg[col[e]], 1);
}
__global__ __launch_bounds__(256) void k_pqtable_fb(
        const float* __restrict__ x, const float* __restrict__ West,
        const float* __restrict__ wcomb, const int* __restrict__ deg,
        float* __restrict__ dinv, float2* __restrict__ table,
        float2* __restrict__ acc) {
    int node = (blockIdx.x * blockDim.x + threadIdx.x) >> 6;
    int lane = threadIdx.x & 63;
    if (node >= N_NODES) return;
    float4 v  = ((const float4*)(x + (size_t)node * N_FEAT))[lane];
    float4 we = ((const float4*)West)[lane];
    float4 wc = ((const float4*)wcomb)[lane];
    float ps = v.x * we.x + v.y * we.y + v.z * we.z + v.w * we.w;
    float qs = v.x * wc.x + v.y * wc.y + v.z * wc.z + v.w * wc.w;
#pragma unroll
    for (int off = 32; off > 0; off >>= 1) {
        ps += __shfl_down(ps, off);
        qs += __shfl_down(qs, off);
    }
    if (lane == 0) {
        float di = rsqrtf((float)(deg[node] + 1));
        float2 t = make_float2(di * qs, di * ps);
        dinv[node] = di; table[node] = t; acc[node] = t;
    }
}
__global__ __launch_bounds__(256) void k_edge_fb(const int* __restrict__ ei,
                                                 const float2* __restrict__ table,
                                                 float2* __restrict__ acc) {
    int e = blockIdx.x * blockDim.x + threadIdx.x;
    if (e >= N_EDGES) return;
    float2 t = table[ei[e]];
    int c = ei[N_EDGES + e];
    unsafeAtomicAdd(&acc[c].x, t.x);
    unsafeAtomicAdd(&acc[c].y, t.y);
}
__global__ __launch_bounds__(256) void k_fin_fb(
        const float* __restrict__ dinv, const float2* __restrict__ acc,
        const float* __restrict__ biasy, const float* __restrict__ best,
        float* __restrict__ out) {
    int i = blockIdx.x * blockDim.x + threadIdx.x;
    if (i >= N_NODES) return;
    float di = dinv[i];
    float2 a = acc[i];
    out[i]           = di * a.x + biasy[0];
    out[N_NODES + i] = di * a.y + best[0];
}

extern "C" void kernel_launch(void* const* d_in, const int* in_sizes, int n_in,
                              void* d_out, int out_size, void* d_ws, size_t ws_size,
                              hipStream_t stream) {
    const int*   ei   = (const int*)d_in[0];
    const float* x    = (const float*)d_in[1];
    const float* West = (const float*)d_in[2];
    const float* best = (const float*)d_in[3];
    const float* Wg   = (const float*)d_in[4];
    const float* bg   = (const float*)d_in[5];
    const float* Wc   = (const float*)d_in[6];
    const float* bc   = (const float*)d_in[7];
    float* out = (float*)d_out;

    // ---- workspace layout (bytes) ----
    char* ws = (char*)d_ws;
    float*  wcomb = (float*)ws;                       // 256 f          @ 0
    float*  biasy = wcomb + 256;                      // 1 f
    float2* pq    = (float2*)(ws + 2048);             // N f2  (800000 B)
    float2* table = (float2*)(ws + 802048);           // N f2  (800000 B)
    float*  dinv  = (float*)(ws + 1602048);           // N f   (400000 B)
    int*    cursor= (int*)(ws + 2002048);             // NBINS i
    unsigned int* grouped = (unsigned int*)(ws + 2003072); // NBINS*BIN_CAP u32
    size_t need = 2003072 + (size_t)NBINS * BIN_CAP * 4;   // ~15.9 MB

    if (ws_size >= need) {
        k_wcomb<<<1, 256, 0, stream>>>(Wg, bg, Wc, bc, wcomb, biasy, cursor);
        k_pqpart<<<NPART + NPQ, 256, 0, stream>>>(x, West, wcomb, pq,
                                                  (const int4*)ei,
                                                  (const int4*)(ei + N_EDGES),
                                                  cursor, grouped);
        k_bindeg<<<NBINS, 256, 0, stream>>>(cursor, grouped, pq, dinv, table);
        k_binacc<<<NBINS, 1024, 0, stream>>>(cursor, grouped, table, dinv,
                                             biasy, best, out);
    } else {
        // fallback: global-atomic pipeline (needs ~2.4 MB)
        int*    deg  = (int*)(ws + 2048 + 800000 * 2 + 400000);
        float2* acc  = pq;       // reuse
        float2* tbl  = table;
        hipMemsetAsync(deg, 0, N_NODES * sizeof(int), stream);
        k_wcomb<<<1, 256, 0, stream>>>(Wg, bg, Wc, bc, wcomb, biasy, (int*)(ws + 2002048));
        k_deg_fb<<<(N_EDGES + 255) / 256, 256, 0, stream>>>(ei + N_EDGES, deg);
        k_pqtable_fb<<<(N_NODES * 64 + 255) / 256, 256, 0, stream>>>(
            x, West, wcomb, deg, dinv, tbl, acc);
        k_edge_fb<<<(N_EDGES + 255) / 256, 256, 0, stream>>>(ei, tbl, acc);
        k_fin_fb<<<(N_NODES + 255) / 256, 256, 0, stream>>>(dinv, acc, biasy, best, out);
    }
}